// Round 3
// baseline (325.453 us; speedup 1.0000x reference)
//
#include <hip/hip_runtime.h>
#include <hip/hip_bf16.h>
#include <math.h>

#define N_TOK 16384
#define BATCH 4
#define DIM   1024
#define HID   256
#define KEEP  11468            // int(16384 * 0.7)
#define MROWS 65536
#define BK    64
#define NKT   (DIM / BK)       // 16
#define DELTA 6e-3f            // exact-recompute window around approx cut
#define WCAP  4096             // max window rows per batch

typedef __attribute__((ext_vector_type(8))) short bf16x8;
typedef __attribute__((ext_vector_type(4))) float f32x4;

__device__ inline unsigned bf16_rne(float f) {
    unsigned u = __float_as_uint(f);
    return (u + 0x7FFFu + ((u >> 16) & 1u)) >> 16;
}

// ---------------------------------------------------------------------------
// prep: pack W1 (f32 [k][h]) into MFMA-B-fragment order, bf16:
// Wpk[kt][ks][hg][lane][8]  (kt: K-tile of 64, ks: 32-k step, hg: 16-col group)
// lane&15 = h within group, (lane>>4)*8+j = k within 32. 16B/lane contiguous.
// ---------------------------------------------------------------------------
__global__ __launch_bounds__(256) void prep_kernel(
    const float* __restrict__ W1, ushort* __restrict__ Wpk)
{
    const int kt = blockIdx.x;   // 0..15
    for (int idx = threadIdx.x; idx < 2048; idx += 256) {
        const int lane = idx & 63;
        const int g    = idx >> 6;        // 0..31 = ks*16 + hg
        const int h    = (g & 15) * 16 + (lane & 15);
        const int kb   = kt * 64 + (g >> 4) * 32 + (lane >> 4) * 8;
        ushort v[8];
#pragma unroll
        for (int j = 0; j < 8; ++j)
            v[j] = (ushort)bf16_rne(W1[(size_t)(kb + j) * HID + h]);
        *(uint4*)(Wpk + ((size_t)(kt * 32 + g) * 64 + lane) * 8) = *(uint4*)v;
    }
}

// ---------------------------------------------------------------------------
// score: scores = sigmoid(relu(x@W1+b1)@W2+b2), 1-pass bf16 MFMA.
// 256 thr (4 waves, wr2 x wc2), block tile 64 rows x 256 cols, wave 32x128.
// A: double-buffered swizzled LDS bf16 [2][64][64] (8KB each).
// B: direct global b128 frag loads from Wpk (L1/L2-hot).
// ---------------------------------------------------------------------------
__global__ __launch_bounds__(256, 3) void score_mfma(
    const float* __restrict__ x, const ushort* __restrict__ Wpk,
    const float* __restrict__ b1, const float* __restrict__ W2,
    const float* __restrict__ b2, float* __restrict__ scores,
    float* __restrict__ partials)
{
    __shared__ ushort As[2][64 * 64];
    __shared__ float zbuf[64][2];
    __shared__ float red[64];

    const int t    = threadIdx.x;
    const int lane = t & 63;
    const int w    = t >> 6;
    const int wr   = w >> 1;
    const int wc   = w & 1;
    const int l15  = lane & 15;
    const int lk   = lane >> 4;
    const size_t row0 = (size_t)blockIdx.x * 64;

    const int arow = t >> 2;     // 0..63
    const int aq   = t & 3;      // 16-float quarter of the 64-k slice
    const float* xbase = x + (row0 + arow) * DIM + aq * 16;

    f32x4 acc[2][8];
#pragma unroll
    for (int rf = 0; rf < 2; ++rf)
#pragma unroll
        for (int cf = 0; cf < 8; ++cf) acc[rf][cf] = (f32x4){0.f, 0.f, 0.f, 0.f};

    float pf[16];
#define LOADA(KT) { const float* xp = xbase + (KT) * BK; \
        *(float4*)&pf[0]  = ((const float4*)xp)[0]; \
        *(float4*)&pf[4]  = ((const float4*)xp)[1]; \
        *(float4*)&pf[8]  = ((const float4*)xp)[2]; \
        *(float4*)&pf[12] = ((const float4*)xp)[3]; }
#define STOREA(BUF) { \
        ushort hb[16]; \
        _Pragma("unroll") \
        for (int j = 0; j < 16; ++j) hb[j] = (ushort)bf16_rne(pf[j]); \
        char* base_ = (char*)&As[BUF][0] + arow * 128; \
        const int swz_ = (arow & 7) << 4; \
        *(uint4*)(base_ + ((aq * 32) ^ swz_))      = *(uint4*)&hb[0]; \
        *(uint4*)(base_ + ((aq * 32 + 16) ^ swz_)) = *(uint4*)&hb[8]; }

    LOADA(0); STOREA(0);
    __syncthreads();

    for (int kt = 0; kt < NKT; ++kt) {
        const int cur = kt & 1;
        if (kt < NKT - 1) LOADA(kt + 1);
#pragma unroll
        for (int ks = 0; ks < 2; ++ks) {
            bf16x8 Af[2];
#pragma unroll
            for (int rf = 0; rf < 2; ++rf) {
                const int row = wr * 32 + rf * 16 + l15;
                const int kb  = (ks * 64 + lk * 16) ^ ((row & 7) << 4);
                Af[rf] = *(const bf16x8*)((const char*)&As[cur][0] + row * 128 + kb);
            }
#pragma unroll
            for (int cf = 0; cf < 8; ++cf) {
                const bf16x8 Bf = *(const bf16x8*)(
                    Wpk + ((size_t)(kt * 32 + ks * 16 + wc * 8 + cf) * 64 + lane) * 8);
                acc[0][cf] = __builtin_amdgcn_mfma_f32_16x16x32_bf16(Af[0], Bf, acc[0][cf], 0, 0, 0);
                acc[1][cf] = __builtin_amdgcn_mfma_f32_16x16x32_bf16(Af[1], Bf, acc[1][cf], 0, 0, 0);
            }
        }
        if (kt < NKT - 1) STOREA(cur ^ 1);
        __syncthreads();
    }

    // epilogue: z = sum_h relu(C + b1) * W2; C row = lk*4+j, col = l15
    float b1r[8], w2r[8];
#pragma unroll
    for (int cf = 0; cf < 8; ++cf) {
        const int col = wc * 128 + cf * 16 + l15;
        b1r[cf] = b1[col];
        w2r[cf] = W2[col];
    }
#pragma unroll
    for (int rf = 0; rf < 2; ++rf) {
#pragma unroll
        for (int j = 0; j < 4; ++j) {
            float z = 0.f;
#pragma unroll
            for (int cf = 0; cf < 8; ++cf)
                z = fmaf(fmaxf(acc[rf][cf][j] + b1r[cf], 0.f), w2r[cf], z);
            z += __shfl_xor(z, 1);
            z += __shfl_xor(z, 2);
            z += __shfl_xor(z, 4);
            z += __shfl_xor(z, 8);
            if (l15 == 0) zbuf[wr * 32 + rf * 16 + lk * 4 + j][wc] = z;
        }
    }
    __syncthreads();
    if (t < 64) {
        const float z = zbuf[t][0] + zbuf[t][1] + b2[0];
        const float s = 1.f / (1.f + expf(-z));
        scores[row0 + t] = s;
        red[t] = fabsf(s - 0.5f);
    }
    __syncthreads();
    for (int off = 32; off > 0; off >>= 1) {
        if (t < off) red[t] += red[t + off];
        __syncthreads();
    }
    if (t == 0) partials[blockIdx.x] = red[0];
}

// ---------------------------------------------------------------------------
// fixfind: per batch, binary-search the approx k-th score, emit the list of
// rows within +-DELTA of it (deterministic order by row index).
// ---------------------------------------------------------------------------
__global__ __launch_bounds__(1024) void fixfind_kernel(
    const float* __restrict__ scores, int* __restrict__ winList,
    int* __restrict__ winCnt)
{
    const int b    = blockIdx.x;
    const int t    = threadIdx.x;
    const int lane = t & 63;
    const int wid  = t >> 6;
    __shared__ unsigned red[17];
    __shared__ unsigned wsum[16];

    float sv[16];
    unsigned bits[16];
    const float4* sp = (const float4*)(scores + (size_t)b * N_TOK + t * 16);
#pragma unroll
    for (int j = 0; j < 4; ++j) {
        const float4 v = sp[j];
        sv[j * 4 + 0] = v.x; sv[j * 4 + 1] = v.y;
        sv[j * 4 + 2] = v.z; sv[j * 4 + 3] = v.w;
    }
#pragma unroll
    for (int j = 0; j < 16; ++j) bits[j] = __float_as_uint(sv[j]);

    auto countGE = [&](unsigned v) -> unsigned {
        unsigned c = 0;
#pragma unroll
        for (int j = 0; j < 16; ++j) c += (bits[j] >= v) ? 1u : 0u;
        c += __shfl_xor(c, 32); c += __shfl_xor(c, 16); c += __shfl_xor(c, 8);
        c += __shfl_xor(c, 4);  c += __shfl_xor(c, 2);  c += __shfl_xor(c, 1);
        if (lane == 0) red[wid] = c;
        __syncthreads();
        if (t == 0) {
            unsigned s = 0;
            for (int w = 0; w < 16; ++w) s += red[w];
            red[16] = s;
        }
        __syncthreads();
        return red[16];
    };

    unsigned lo = 0u, hi = 0x40000000u;
    while (hi - lo > 1u) {
        const unsigned mid = (lo + hi) >> 1;
        if (countGE(mid) >= KEEP) lo = mid; else hi = mid;
    }
    const float sT = __uint_as_float(lo);

    int cnt = 0;
    bool inw[16];
#pragma unroll
    for (int j = 0; j < 16; ++j) {
        inw[j] = fabsf(sv[j] - sT) <= DELTA;
        cnt += inw[j] ? 1 : 0;
    }
    unsigned inc = (unsigned)cnt;
#pragma unroll
    for (int off = 1; off < 64; off <<= 1) {
        const unsigned n = __shfl_up(inc, off);
        if (lane >= off) inc += n;
    }
    const unsigned excl = inc - (unsigned)cnt;
    if (lane == 63) wsum[wid] = inc;
    __syncthreads();
    if (t == 0) {
        unsigned s = 0;
        for (int w = 0; w < 16; ++w) { const unsigned tmp = wsum[w]; wsum[w] = s; s += tmp; }
        winCnt[b] = (int)(s > WCAP ? WCAP : s);
    }
    __syncthreads();
    unsigned pos = wsum[wid] + excl;
#pragma unroll
    for (int j = 0; j < 16; ++j) {
        if (inw[j]) {
            if (pos < WCAP) winList[b * WCAP + pos] = t * 16 + j;
            ++pos;
        }
    }
}

// ---------------------------------------------------------------------------
// fix2: exact f32 recompute of windowed rows, 8 rows/group, 1024 threads,
// k-dim split over 4 thread-quads. Grid-stride over groups.
// ---------------------------------------------------------------------------
__global__ __launch_bounds__(1024) void fix2_kernel(
    const float* __restrict__ x, const float* __restrict__ W1,
    const float* __restrict__ b1, const float* __restrict__ W2,
    const float* __restrict__ b2, float* __restrict__ scores,
    const int* __restrict__ winList, const int* __restrict__ winCnt)
{
    __shared__ float xrT[1024][8];
    __shared__ float part[4][8][256];
    __shared__ int rows[8];

    const int t = threadIdx.x;
    int c[4], cum[5];
    cum[0] = 0;
    for (int b = 0; b < 4; ++b) {
        int cc = winCnt[b];
        if (cc > WCAP) cc = WCAP;
        if (cc < 0) cc = 0;
        c[b] = cc;
        cum[b + 1] = cum[b] + ((cc + 7) >> 3);
    }
    for (int g = blockIdx.x; g < cum[4]; g += gridDim.x) {
        int b = 0;
        while (g >= cum[b + 1]) ++b;
        const int gi   = g - cum[b];
        const int nval = min(8, c[b] - gi * 8);
        if (t < 8)
            rows[t] = winList[b * WCAP + gi * 8 + (t < nval ? t : 0)];
        __syncthreads();
        {
            const int r = t >> 7, c0 = (t & 127) * 8;
            const float* xp = x + ((size_t)b * N_TOK + rows[r]) * DIM + c0;
            const float4 a = ((const float4*)xp)[0], bq = ((const float4*)xp)[1];
            xrT[c0 + 0][r] = a.x;  xrT[c0 + 1][r] = a.y;
            xrT[c0 + 2][r] = a.z;  xrT[c0 + 3][r] = a.w;
            xrT[c0 + 4][r] = bq.x; xrT[c0 + 5][r] = bq.y;
            xrT[c0 + 6][r] = bq.z; xrT[c0 + 7][r] = bq.w;
        }
        __syncthreads();
        const int h = t & 255, q = t >> 8;
        float a8[8];
#pragma unroll
        for (int r = 0; r < 8; ++r) a8[r] = 0.f;
        const int k0 = q * 256;
        for (int k = 0; k < 256; ++k) {
            const float wv = W1[(size_t)(k0 + k) * HID + h];
            const float4 xa = *(const float4*)&xrT[k0 + k][0];
            const float4 xb = *(const float4*)&xrT[k0 + k][4];
            a8[0] = fmaf(xa.x, wv, a8[0]); a8[1] = fmaf(xa.y, wv, a8[1]);
            a8[2] = fmaf(xa.z, wv, a8[2]); a8[3] = fmaf(xa.w, wv, a8[3]);
            a8[4] = fmaf(xb.x, wv, a8[4]); a8[5] = fmaf(xb.y, wv, a8[5]);
            a8[6] = fmaf(xb.z, wv, a8[6]); a8[7] = fmaf(xb.w, wv, a8[7]);
        }
#pragma unroll
        for (int r = 0; r < 8; ++r) part[q][r][h] = a8[r];
        __syncthreads();
        const int wid = t >> 6, lane = t & 63;
        if (wid < 8) {
            const int r = wid;
            float v = 0.f;
#pragma unroll
            for (int i = 0; i < 4; ++i) {
                const int hc = i * 64 + lane;
                float hv = (part[0][r][hc] + part[1][r][hc]) + (part[2][r][hc] + part[3][r][hc]);
                hv = fmaxf(hv + b1[hc], 0.f);
                v = fmaf(hv, W2[hc], v);
            }
            v += __shfl_xor(v, 32); v += __shfl_xor(v, 16); v += __shfl_xor(v, 8);
            v += __shfl_xor(v, 4);  v += __shfl_xor(v, 2);  v += __shfl_xor(v, 1);
            if (lane == 0 && r < nval)
                scores[(size_t)b * N_TOK + rows[r]] = 1.f / (1.f + expf(-(v + b2[0])));
        }
        __syncthreads();
    }
}

// ---------------------------------------------------------------------------
// select: exact top-k per batch on corrected scores (unchanged, verified).
// ---------------------------------------------------------------------------
__global__ __launch_bounds__(1024) void select_kernel(
    const float* __restrict__ scores, int* __restrict__ idxList)
{
    const int b    = blockIdx.x;
    const int t    = threadIdx.x;
    const int lane = t & 63;
    const int wid  = t >> 6;
    __shared__ unsigned red[17];

    unsigned bits[16];
    const float4* sp = (const float4*)(scores + (size_t)b * N_TOK + t * 16);
#pragma unroll
    for (int j = 0; j < 4; ++j) {
        const float4 v = sp[j];
        bits[j * 4 + 0] = __float_as_uint(v.x);
        bits[j * 4 + 1] = __float_as_uint(v.y);
        bits[j * 4 + 2] = __float_as_uint(v.z);
        bits[j * 4 + 3] = __float_as_uint(v.w);
    }

    auto countGE = [&](unsigned v) -> unsigned {
        unsigned c = 0;
#pragma unroll
        for (int j = 0; j < 16; ++j) c += (bits[j] >= v) ? 1u : 0u;
        c += __shfl_xor(c, 32); c += __shfl_xor(c, 16); c += __shfl_xor(c, 8);
        c += __shfl_xor(c, 4);  c += __shfl_xor(c, 2);  c += __shfl_xor(c, 1);
        if (lane == 0) red[wid] = c;
        __syncthreads();
        if (t == 0) {
            unsigned s = 0;
            for (int w = 0; w < 16; ++w) s += red[w];
            red[16] = s;
        }
        __syncthreads();
        return red[16];
    };

    unsigned lo = 0u, hi = 0x40000000u;
    while (hi - lo > 1u) {
        const unsigned mid = (lo + hi) >> 1;
        if (countGE(mid) >= KEEP) lo = mid; else hi = mid;
    }
    const unsigned T    = lo;
    const unsigned cGT  = countGE(T + 1u);
    const unsigned need = KEEP - cGT;

    unsigned pre[16];
    unsigned run = 0;
#pragma unroll
    for (int j = 0; j < 16; ++j) {
        pre[j] = run;
        const unsigned gt = (bits[j] > T) ? 1u : 0u;
        const unsigned eq = (bits[j] == T) ? 1u : 0u;
        run += gt | (eq << 16);
    }
    unsigned inc = run;
#pragma unroll
    for (int off = 1; off < 64; off <<= 1) {
        const unsigned n = __shfl_up(inc, off);
        if (lane >= off) inc += n;
    }
    const unsigned waveExcl = inc - run;
    if (lane == 63) red[wid] = inc;
    __syncthreads();
    if (t == 0) {
        unsigned s = 0;
        for (int w = 0; w < 16; ++w) { const unsigned tmp = red[w]; red[w] = s; s += tmp; }
    }
    __syncthreads();
    const unsigned base = red[wid] + waveExcl;

#pragma unroll
    for (int j = 0; j < 16; ++j) {
        const unsigned pe    = base + pre[j];
        const unsigned tieR  = pe >> 16;
        const unsigned posGT = pe & 0xFFFFu;
        const bool gt = bits[j] > T;
        const bool eq = bits[j] == T;
        if (gt || (eq && tieR < need)) {
            const unsigned pos = posGT + (tieR < need ? tieR : need);
            idxList[(size_t)b * KEEP + pos] = t * 16 + j;
        }
    }
}

// ---------------------------------------------------------------------------
// gather: weighted gather, float4 (HBM-bound).
// ---------------------------------------------------------------------------
__global__ __launch_bounds__(256) void gather_kernel(
    const float* __restrict__ x, const float* __restrict__ scores,
    const int* __restrict__ idxList, float* __restrict__ out)
{
    const int t = threadIdx.x;
#pragma unroll
    for (int q = 0; q < 4; ++q) {
        const int orow = blockIdx.x * 4 + q;
        const int b    = orow / KEEP;
        const int idx  = idxList[orow];
        const float s  = scores[(size_t)b * N_TOK + idx];
        const float4 v = *(const float4*)(x + (((size_t)b * N_TOK + idx) << 10) + t * 4);
        float4 o;
        o.x = v.x * s; o.y = v.y * s; o.z = v.z * s; o.w = v.w * s;
        *(float4*)(out + ((size_t)orow << 10) + t * 4) = o;
    }
}

// ---------------------------------------------------------------------------
// loss: -mean(|s-0.5|) over 1024 block partials.
// ---------------------------------------------------------------------------
__global__ __launch_bounds__(256) void loss_kernel(
    const float* __restrict__ partials, float* __restrict__ outLoss)
{
    __shared__ float red[256];
    const int t = threadIdx.x;
    red[t] = (partials[t] + partials[t + 256]) + (partials[t + 512] + partials[t + 768]);
    __syncthreads();
    for (int off = 128; off > 0; off >>= 1) {
        if (t < off) red[t] += red[t + off];
        __syncthreads();
    }
    if (t == 0) outLoss[0] = -(red[0] / (float)MROWS);
}

extern "C" void kernel_launch(void* const* d_in, const int* in_sizes, int n_in,
                              void* d_out, int out_size, void* d_ws, size_t ws_size,
                              hipStream_t stream)
{
    const float* x  = (const float*)d_in[0];
    const float* W1 = (const float*)d_in[1];
    const float* b1 = (const float*)d_in[2];
    const float* W2 = (const float*)d_in[3];
    const float* b2 = (const float*)d_in[4];
    float* out = (float*)d_out;

    char* ws = (char*)d_ws;
    float* scores   = (float*)ws;                 // 262144 B
    float* partials = (float*)(ws + 262144);      // 4096 B
    int*   idxList  = (int*)(ws + 266240);        // 183488 B
    ushort* Wpk     = (ushort*)(ws + 458752);     // 524288 B
    int*   winList  = (int*)(ws + 983040);        // 65536 B
    int*   winCnt   = (int*)(ws + 1048576);       // 16 B

    prep_kernel<<<NKT, 256, 0, stream>>>(W1, Wpk);
    score_mfma<<<MROWS / 64, 256, 0, stream>>>(x, Wpk, b1, W2, b2, scores, partials);
    loss_kernel<<<1, 256, 0, stream>>>(partials, out + (size_t)BATCH * KEEP * DIM);
    fixfind_kernel<<<BATCH, 1024, 0, stream>>>(scores, winList, winCnt);
    fix2_kernel<<<256, 1024, 0, stream>>>(x, W1, b1, W2, b2, scores, winList, winCnt);
    select_kernel<<<BATCH, 1024, 0, stream>>>(scores, idxList);
    gather_kernel<<<KEEP, 256, 0, stream>>>(x, scores, idxList, out);
}

// Round 4
// 240.065 us; speedup vs baseline: 1.3557x; 1.3557x over previous
//
#include <hip/hip_runtime.h>
#include <hip/hip_bf16.h>
#include <math.h>

#define N_TOK 16384
#define BATCH 4
#define DIM   1024
#define HID   256
#define KEEP  11468            // int(16384 * 0.7)
#define MROWS 65536
#define BK    64
#define NKT   (DIM / BK)       // 16
#define DELTA 6e-3f            // exact-recompute window around approx cut
#define WCAP  4096             // max window rows per batch

typedef __attribute__((ext_vector_type(8))) short bf16x8;
typedef __attribute__((ext_vector_type(4))) float f32x4;

__device__ inline unsigned bf16_rne(float f) {
    unsigned u = __float_as_uint(f);
    return (u + 0x7FFFu + ((u >> 16) & 1u)) >> 16;
}

#define GLDS16(gp, lp) __builtin_amdgcn_global_load_lds( \
    (const __attribute__((address_space(1))) void*)(gp), \
    (__attribute__((address_space(3))) void*)(lp), 16, 0, 0)

// ---------------------------------------------------------------------------
// prep: pack W1 (f32 [k][h]) into MFMA-B-fragment order, bf16:
// Wpk[kt][g][lane][8]  g = ks*16+hg; h=(g&15)*16+(lane&15),
// k = kt*64 + (g>>4)*32 + (lane>>4)*8 + j.  Each g-line = 64 lanes x 16B.
// ---------------------------------------------------------------------------
__global__ __launch_bounds__(256) void prep_kernel(
    const float* __restrict__ W1, ushort* __restrict__ Wpk)
{
    const int kt = blockIdx.x;   // 0..15
    for (int idx = threadIdx.x; idx < 2048; idx += 256) {
        const int lane = idx & 63;
        const int g    = idx >> 6;        // 0..31
        const int h    = (g & 15) * 16 + (lane & 15);
        const int kb   = kt * 64 + (g >> 4) * 32 + (lane >> 4) * 8;
        ushort v[8];
#pragma unroll
        for (int j = 0; j < 8; ++j)
            v[j] = (ushort)bf16_rne(W1[(size_t)(kb + j) * HID + h]);
        *(uint4*)(Wpk + ((size_t)(kt * 32 + g) * 64 + lane) * 8) = *(uint4*)v;
    }
}

// ---------------------------------------------------------------------------
// score: scores = sigmoid(relu(x@W1+b1)@W2+b2), 1-pass bf16 MFMA.
// 512 thr = 8 waves (2 wr x 4 wc), block tile 128 rows x 256 cols, wave 64x64.
// A: double-buffered XOR-swizzled LDS bf16 [2][128][64] (reg-staged, cvt).
// B: double-buffered linear LDS [2][32 lines][1KB] via global_load_lds w=16.
// One barrier per K-iter; loads for kt+1 issued before compute of kt.
// ---------------------------------------------------------------------------
__global__ __launch_bounds__(512, 2) void score_mfma(
    const float* __restrict__ x, const ushort* __restrict__ Wpk,
    const float* __restrict__ b1, const float* __restrict__ W2,
    const float* __restrict__ b2, float* __restrict__ scores,
    float* __restrict__ partials)
{
    __shared__ ushort As[2][128 * 64];
    __shared__ ushort Bs[2][32 * 512];
    __shared__ float zbuf[128][4];
    __shared__ float red[128];

    const int t    = threadIdx.x;
    const int lane = t & 63;
    const int w    = t >> 6;         // 0..7
    const int wr   = w >> 2;         // 0..1  (64 rows each)
    const int wc   = w & 3;          // 0..3  (64 cols each)
    const int l15  = lane & 15;
    const int lk   = lane >> 4;
    const size_t row0 = (size_t)blockIdx.x * 128;

    const int arow = t >> 2;         // 0..127
    const int aq   = t & 3;          // 16-float quarter of 64-k slice
    const float* xbase = x + (row0 + arow) * DIM + aq * 16;

    f32x4 acc[4][4];
#pragma unroll
    for (int rf = 0; rf < 4; ++rf)
#pragma unroll
        for (int cf = 0; cf < 4; ++cf) acc[rf][cf] = (f32x4){0.f, 0.f, 0.f, 0.f};

    float pf[16];
#define LOADA(KT) { const float* xp = xbase + (KT) * BK; \
        *(float4*)&pf[0]  = ((const float4*)xp)[0]; \
        *(float4*)&pf[4]  = ((const float4*)xp)[1]; \
        *(float4*)&pf[8]  = ((const float4*)xp)[2]; \
        *(float4*)&pf[12] = ((const float4*)xp)[3]; }
#define STOREA(BUF) { \
        ushort hb[16]; \
        _Pragma("unroll") \
        for (int j = 0; j < 16; ++j) hb[j] = (ushort)bf16_rne(pf[j]); \
        char* base_ = (char*)&As[BUF][0] + arow * 128; \
        const int swz_ = (arow & 7) << 4; \
        *(uint4*)(base_ + ((aq * 32) ^ swz_))      = *(uint4*)&hb[0]; \
        *(uint4*)(base_ + ((aq * 32 + 16) ^ swz_)) = *(uint4*)&hb[8]; }
#define LOADB(KT, BUF) { \
        _Pragma("unroll") \
        for (int i = 0; i < 4; ++i) { \
            const int g_ = w * 4 + i; \
            GLDS16(Wpk + (((size_t)(KT) * 32 + g_) * 64 + lane) * 8, \
                   &Bs[BUF][g_ * 512 + lane * 8]); \
        } }

    // prologue: stage kt=0
    LOADB(0, 0);
    LOADA(0);
    STOREA(0);
    __syncthreads();

    for (int kt = 0; kt < NKT; ++kt) {
        const int cur = kt & 1;
        const int nxt = cur ^ 1;
        if (kt < NKT - 1) {
            LOADB(kt + 1, nxt);
            LOADA(kt + 1);
        }
#pragma unroll
        for (int ks = 0; ks < 2; ++ks) {
            bf16x8 Af[4];
#pragma unroll
            for (int rf = 0; rf < 4; ++rf) {
                const int row = wr * 64 + rf * 16 + l15;
                const int kb  = (ks * 64 + lk * 16) ^ ((row & 7) << 4);
                Af[rf] = *(const bf16x8*)((const char*)&As[cur][0] + row * 128 + kb);
            }
#pragma unroll
            for (int cf = 0; cf < 4; ++cf) {
                const int g = ks * 16 + wc * 4 + cf;
                const bf16x8 Bf = *(const bf16x8*)&Bs[cur][g * 512 + lane * 8];
                acc[0][cf] = __builtin_amdgcn_mfma_f32_16x16x32_bf16(Af[0], Bf, acc[0][cf], 0, 0, 0);
                acc[1][cf] = __builtin_amdgcn_mfma_f32_16x16x32_bf16(Af[1], Bf, acc[1][cf], 0, 0, 0);
                acc[2][cf] = __builtin_amdgcn_mfma_f32_16x16x32_bf16(Af[2], Bf, acc[2][cf], 0, 0, 0);
                acc[3][cf] = __builtin_amdgcn_mfma_f32_16x16x32_bf16(Af[3], Bf, acc[3][cf], 0, 0, 0);
            }
        }
        if (kt < NKT - 1) STOREA(nxt);
        __syncthreads();
    }

    // epilogue: z = sum_h relu(C + b1) * W2; C row = lk*4+j, col = l15
    float b1r[4], w2r[4];
#pragma unroll
    for (int cf = 0; cf < 4; ++cf) {
        const int col = wc * 64 + cf * 16 + l15;
        b1r[cf] = b1[col];
        w2r[cf] = W2[col];
    }
#pragma unroll
    for (int rf = 0; rf < 4; ++rf) {
#pragma unroll
        for (int j = 0; j < 4; ++j) {
            float z = 0.f;
#pragma unroll
            for (int cf = 0; cf < 4; ++cf)
                z = fmaf(fmaxf(acc[rf][cf][j] + b1r[cf], 0.f), w2r[cf], z);
            z += __shfl_xor(z, 1);
            z += __shfl_xor(z, 2);
            z += __shfl_xor(z, 4);
            z += __shfl_xor(z, 8);
            if (l15 == 0) zbuf[wr * 64 + rf * 16 + lk * 4 + j][wc] = z;
        }
    }
    __syncthreads();
    if (t < 128) {
        const float z = (zbuf[t][0] + zbuf[t][1]) + (zbuf[t][2] + zbuf[t][3]) + b2[0];
        const float s = 1.f / (1.f + expf(-z));
        scores[row0 + t] = s;
        red[t] = fabsf(s - 0.5f);
    }
    __syncthreads();
    for (int off = 64; off > 0; off >>= 1) {
        if (t < off) red[t] += red[t + off];
        __syncthreads();
    }
    if (t == 0) partials[blockIdx.x] = red[0];
}

// ---------------------------------------------------------------------------
// fixfind: per batch, binary-search the approx k-th score, emit rows within
// +-DELTA (deterministic order by row index).
// ---------------------------------------------------------------------------
__global__ __launch_bounds__(1024) void fixfind_kernel(
    const float* __restrict__ scores, int* __restrict__ winList,
    int* __restrict__ winCnt)
{
    const int b    = blockIdx.x;
    const int t    = threadIdx.x;
    const int lane = t & 63;
    const int wid  = t >> 6;
    __shared__ unsigned red[17];
    __shared__ unsigned wsum[16];

    float sv[16];
    unsigned bits[16];
    const float4* sp = (const float4*)(scores + (size_t)b * N_TOK + t * 16);
#pragma unroll
    for (int j = 0; j < 4; ++j) {
        const float4 v = sp[j];
        sv[j * 4 + 0] = v.x; sv[j * 4 + 1] = v.y;
        sv[j * 4 + 2] = v.z; sv[j * 4 + 3] = v.w;
    }
#pragma unroll
    for (int j = 0; j < 16; ++j) bits[j] = __float_as_uint(sv[j]);

    auto countGE = [&](unsigned v) -> unsigned {
        unsigned c = 0;
#pragma unroll
        for (int j = 0; j < 16; ++j) c += (bits[j] >= v) ? 1u : 0u;
        c += __shfl_xor(c, 32); c += __shfl_xor(c, 16); c += __shfl_xor(c, 8);
        c += __shfl_xor(c, 4);  c += __shfl_xor(c, 2);  c += __shfl_xor(c, 1);
        if (lane == 0) red[wid] = c;
        __syncthreads();
        if (t == 0) {
            unsigned s = 0;
            for (int w = 0; w < 16; ++w) s += red[w];
            red[16] = s;
        }
        __syncthreads();
        return red[16];
    };

    unsigned lo = 0u, hi = 0x40000000u;
    while (hi - lo > 1u) {
        const unsigned mid = (lo + hi) >> 1;
        if (countGE(mid) >= KEEP) lo = mid; else hi = mid;
    }
    const float sT = __uint_as_float(lo);

    int cnt = 0;
    bool inw[16];
#pragma unroll
    for (int j = 0; j < 16; ++j) {
        inw[j] = fabsf(sv[j] - sT) <= DELTA;
        cnt += inw[j] ? 1 : 0;
    }
    unsigned inc = (unsigned)cnt;
#pragma unroll
    for (int off = 1; off < 64; off <<= 1) {
        const unsigned n = __shfl_up(inc, off);
        if (lane >= off) inc += n;
    }
    const unsigned excl = inc - (unsigned)cnt;
    if (lane == 63) wsum[wid] = inc;
    __syncthreads();
    if (t == 0) {
        unsigned s = 0;
        for (int w = 0; w < 16; ++w) { const unsigned tmp = wsum[w]; wsum[w] = s; s += tmp; }
        winCnt[b] = (int)(s > WCAP ? WCAP : s);
    }
    __syncthreads();
    unsigned pos = wsum[wid] + excl;
#pragma unroll
    for (int j = 0; j < 16; ++j) {
        if (inw[j]) {
            if (pos < WCAP) winList[b * WCAP + pos] = t * 16 + j;
            ++pos;
        }
    }
}

// ---------------------------------------------------------------------------
// fix2: exact f32 recompute of windowed rows, 8 rows/group, 1024 threads,
// k-dim split over 4 thread-quads. Grid-stride over groups.
// ---------------------------------------------------------------------------
__global__ __launch_bounds__(1024) void fix2_kernel(
    const float* __restrict__ x, const float* __restrict__ W1,
    const float* __restrict__ b1, const float* __restrict__ W2,
    const float* __restrict__ b2, float* __restrict__ scores,
    const int* __restrict__ winList, const int* __restrict__ winCnt)
{
    __shared__ float xrT[1024][8];
    __shared__ float part[4][8][256];
    __shared__ int rows[8];

    const int t = threadIdx.x;
    int c[4], cum[5];
    cum[0] = 0;
    for (int b = 0; b < 4; ++b) {
        int cc = winCnt[b];
        if (cc > WCAP) cc = WCAP;
        if (cc < 0) cc = 0;
        c[b] = cc;
        cum[b + 1] = cum[b] + ((cc + 7) >> 3);
    }
    for (int g = blockIdx.x; g < cum[4]; g += gridDim.x) {
        int b = 0;
        while (g >= cum[b + 1]) ++b;
        const int gi   = g - cum[b];
        const int nval = min(8, c[b] - gi * 8);
        if (t < 8)
            rows[t] = winList[b * WCAP + gi * 8 + (t < nval ? t : 0)];
        __syncthreads();
        {
            const int r = t >> 7, c0 = (t & 127) * 8;
            const float* xp = x + ((size_t)b * N_TOK + rows[r]) * DIM + c0;
            const float4 a = ((const float4*)xp)[0], bq = ((const float4*)xp)[1];
            xrT[c0 + 0][r] = a.x;  xrT[c0 + 1][r] = a.y;
            xrT[c0 + 2][r] = a.z;  xrT[c0 + 3][r] = a.w;
            xrT[c0 + 4][r] = bq.x; xrT[c0 + 5][r] = bq.y;
            xrT[c0 + 6][r] = bq.z; xrT[c0 + 7][r] = bq.w;
        }
        __syncthreads();
        const int h = t & 255, q = t >> 8;
        float a8[8];
#pragma unroll
        for (int r = 0; r < 8; ++r) a8[r] = 0.f;
        const int k0 = q * 256;
        for (int k = 0; k < 256; ++k) {
            const float wv = W1[(size_t)(k0 + k) * HID + h];
            const float4 xa = *(const float4*)&xrT[k0 + k][0];
            const float4 xb = *(const float4*)&xrT[k0 + k][4];
            a8[0] = fmaf(xa.x, wv, a8[0]); a8[1] = fmaf(xa.y, wv, a8[1]);
            a8[2] = fmaf(xa.z, wv, a8[2]); a8[3] = fmaf(xa.w, wv, a8[3]);
            a8[4] = fmaf(xb.x, wv, a8[4]); a8[5] = fmaf(xb.y, wv, a8[5]);
            a8[6] = fmaf(xb.z, wv, a8[6]); a8[7] = fmaf(xb.w, wv, a8[7]);
        }
#pragma unroll
        for (int r = 0; r < 8; ++r) part[q][r][h] = a8[r];
        __syncthreads();
        const int wid = t >> 6, lane = t & 63;
        if (wid < 8) {
            const int r = wid;
            float v = 0.f;
#pragma unroll
            for (int i = 0; i < 4; ++i) {
                const int hc = i * 64 + lane;
                float hv = (part[0][r][hc] + part[1][r][hc]) + (part[2][r][hc] + part[3][r][hc]);
                hv = fmaxf(hv + b1[hc], 0.f);
                v = fmaf(hv, W2[hc], v);
            }
            v += __shfl_xor(v, 32); v += __shfl_xor(v, 16); v += __shfl_xor(v, 8);
            v += __shfl_xor(v, 4);  v += __shfl_xor(v, 2);  v += __shfl_xor(v, 1);
            if (lane == 0 && r < nval)
                scores[(size_t)b * N_TOK + rows[r]] = 1.f / (1.f + expf(-(v + b2[0])));
        }
        __syncthreads();
    }
}

// ---------------------------------------------------------------------------
// select: exact top-k per batch on corrected scores (verified).
// ---------------------------------------------------------------------------
__global__ __launch_bounds__(1024) void select_kernel(
    const float* __restrict__ scores, int* __restrict__ idxList)
{
    const int b    = blockIdx.x;
    const int t    = threadIdx.x;
    const int lane = t & 63;
    const int wid  = t >> 6;
    __shared__ unsigned red[17];

    unsigned bits[16];
    const float4* sp = (const float4*)(scores + (size_t)b * N_TOK + t * 16);
#pragma unroll
    for (int j = 0; j < 4; ++j) {
        const float4 v = sp[j];
        bits[j * 4 + 0] = __float_as_uint(v.x);
        bits[j * 4 + 1] = __float_as_uint(v.y);
        bits[j * 4 + 2] = __float_as_uint(v.z);
        bits[j * 4 + 3] = __float_as_uint(v.w);
    }

    auto countGE = [&](unsigned v) -> unsigned {
        unsigned c = 0;
#pragma unroll
        for (int j = 0; j < 16; ++j) c += (bits[j] >= v) ? 1u : 0u;
        c += __shfl_xor(c, 32); c += __shfl_xor(c, 16); c += __shfl_xor(c, 8);
        c += __shfl_xor(c, 4);  c += __shfl_xor(c, 2);  c += __shfl_xor(c, 1);
        if (lane == 0) red[wid] = c;
        __syncthreads();
        if (t == 0) {
            unsigned s = 0;
            for (int w = 0; w < 16; ++w) s += red[w];
            red[16] = s;
        }
        __syncthreads();
        return red[16];
    };

    unsigned lo = 0u, hi = 0x40000000u;
    while (hi - lo > 1u) {
        const unsigned mid = (lo + hi) >> 1;
        if (countGE(mid) >= KEEP) lo = mid; else hi = mid;
    }
    const unsigned T    = lo;
    const unsigned cGT  = countGE(T + 1u);
    const unsigned need = KEEP - cGT;

    unsigned pre[16];
    unsigned run = 0;
#pragma unroll
    for (int j = 0; j < 16; ++j) {
        pre[j] = run;
        const unsigned gt = (bits[j] > T) ? 1u : 0u;
        const unsigned eq = (bits[j] == T) ? 1u : 0u;
        run += gt | (eq << 16);
    }
    unsigned inc = run;
#pragma unroll
    for (int off = 1; off < 64; off <<= 1) {
        const unsigned n = __shfl_up(inc, off);
        if (lane >= off) inc += n;
    }
    const unsigned waveExcl = inc - run;
    if (lane == 63) red[wid] = inc;
    __syncthreads();
    if (t == 0) {
        unsigned s = 0;
        for (int w = 0; w < 16; ++w) { const unsigned tmp = red[w]; red[w] = s; s += tmp; }
    }
    __syncthreads();
    const unsigned base = red[wid] + waveExcl;

#pragma unroll
    for (int j = 0; j < 16; ++j) {
        const unsigned pe    = base + pre[j];
        const unsigned tieR  = pe >> 16;
        const unsigned posGT = pe & 0xFFFFu;
        const bool gt = bits[j] > T;
        const bool eq = bits[j] == T;
        if (gt || (eq && tieR < need)) {
            const unsigned pos = posGT + (tieR < need ? tieR : need);
            idxList[(size_t)b * KEEP + pos] = t * 16 + j;
        }
    }
}

// ---------------------------------------------------------------------------
// gather: weighted gather, float4 (HBM-bound).
// ---------------------------------------------------------------------------
__global__ __launch_bounds__(256) void gather_kernel(
    const float* __restrict__ x, const float* __restrict__ scores,
    const int* __restrict__ idxList, float* __restrict__ out)
{
    const int t = threadIdx.x;
#pragma unroll
    for (int q = 0; q < 4; ++q) {
        const int orow = blockIdx.x * 4 + q;
        const int b    = orow / KEEP;
        const int idx  = idxList[orow];
        const float s  = scores[(size_t)b * N_TOK + idx];
        const float4 v = *(const float4*)(x + (((size_t)b * N_TOK + idx) << 10) + t * 4);
        float4 o;
        o.x = v.x * s; o.y = v.y * s; o.z = v.z * s; o.w = v.w * s;
        *(float4*)(out + ((size_t)orow << 10) + t * 4) = o;
    }
}

// ---------------------------------------------------------------------------
// loss: -mean(|s-0.5|) over 512 block partials.
// ---------------------------------------------------------------------------
__global__ __launch_bounds__(256) void loss_kernel(
    const float* __restrict__ partials, float* __restrict__ outLoss)
{
    __shared__ float red[256];
    const int t = threadIdx.x;
    red[t] = partials[t] + partials[t + 256];
    __syncthreads();
    for (int off = 128; off > 0; off >>= 1) {
        if (t < off) red[t] += red[t + off];
        __syncthreads();
    }
    if (t == 0) outLoss[0] = -(red[0] / (float)MROWS);
}

extern "C" void kernel_launch(void* const* d_in, const int* in_sizes, int n_in,
                              void* d_out, int out_size, void* d_ws, size_t ws_size,
                              hipStream_t stream)
{
    const float* x  = (const float*)d_in[0];
    const float* W1 = (const float*)d_in[1];
    const float* b1 = (const float*)d_in[2];
    const float* W2 = (const float*)d_in[3];
    const float* b2 = (const float*)d_in[4];
    float* out = (float*)d_out;

    char* ws = (char*)d_ws;
    float* scores   = (float*)ws;                 // 262144 B
    float* partials = (float*)(ws + 262144);      // 4096 B (512 used)
    int*   idxList  = (int*)(ws + 266240);        // 183488 B
    ushort* Wpk     = (ushort*)(ws + 458752);     // 524288 B
    int*   winList  = (int*)(ws + 983040);        // 65536 B
    int*   winCnt   = (int*)(ws + 1048576);       // 16 B

    prep_kernel<<<NKT, 256, 0, stream>>>(W1, Wpk);
    score_mfma<<<MROWS / 128, 512, 0, stream>>>(x, Wpk, b1, W2, b2, scores, partials);
    loss_kernel<<<1, 256, 0, stream>>>(partials, out + (size_t)BATCH * KEEP * DIM);
    fixfind_kernel<<<BATCH, 1024, 0, stream>>>(scores, winList, winCnt);
    fix2_kernel<<<256, 1024, 0, stream>>>(x, W1, b1, W2, b2, scores, winList, winCnt);
    select_kernel<<<BATCH, 1024, 0, stream>>>(scores, idxList);
    gather_kernel<<<KEEP, 256, 0, stream>>>(x, scores, idxList, out);
}

// Round 5
// 229.412 us; speedup vs baseline: 1.4186x; 1.0464x over previous
//
#include <hip/hip_runtime.h>
#include <hip/hip_bf16.h>
#include <math.h>

#define N_TOK 16384
#define BATCH 4
#define DIM   1024
#define HID   256
#define KEEP  11468            // int(16384 * 0.7)
#define MROWS 65536
#define BK    32
#define NKT   (DIM / BK)       // 32 K-iters
#define DELTA 6e-3f            // exact-recompute window around approx cut
#define WCAP  4096             // max window rows per batch
#define AP    40               // A row pitch in ushorts (80B: pad kills conflicts)

typedef __attribute__((ext_vector_type(8))) short bf16x8;
typedef __attribute__((ext_vector_type(4))) float f32x4;

__device__ inline unsigned bf16_rne(float f) {
    unsigned u = __float_as_uint(f);
    return (u + 0x7FFFu + ((u >> 16) & 1u)) >> 16;
}

#define GLDS16(gp, lp) __builtin_amdgcn_global_load_lds( \
    (const __attribute__((address_space(1))) void*)(gp), \
    (__attribute__((address_space(3))) void*)(lp), 16, 0, 0)

// ---------------------------------------------------------------------------
// prep: pack W1 (f32 [k][h]) into MFMA-B-fragment lines, bf16:
// line L = K32*16 + hg  (K32: 32-k block, hg: 16-col group);
// within line: lane&15 = h offset, (lane>>4)*8+j = k offset; 16B/lane.
// ---------------------------------------------------------------------------
__global__ __launch_bounds__(256) void prep_kernel(
    const float* __restrict__ W1, ushort* __restrict__ Wpk)
{
    const int kt = blockIdx.x;   // 0..15 (64-k super-tile; layout is identical)
    for (int idx = threadIdx.x; idx < 2048; idx += 256) {
        const int lane = idx & 63;
        const int g    = idx >> 6;        // 0..31
        const int h    = (g & 15) * 16 + (lane & 15);
        const int kb   = kt * 64 + (g >> 4) * 32 + (lane >> 4) * 8;
        ushort v[8];
#pragma unroll
        for (int j = 0; j < 8; ++j)
            v[j] = (ushort)bf16_rne(W1[(size_t)(kb + j) * HID + h]);
        *(uint4*)(Wpk + ((size_t)(kt * 32 + g) * 64 + lane) * 8) = *(uint4*)v;
    }
}

// ---------------------------------------------------------------------------
// score: scores = sigmoid(relu(x@W1+b1)@W2+b2), 1-pass bf16 MFMA.
// 512 thr = 8 waves (2 wr x 4 wc), block tile 128 x 256, wave 64x64, BK=32.
// A: dbuf padded LDS bf16 [2][128][AP] (reg-staged f32->bf16).
// B: dbuf linear LDS [2][16 lines x 1KB] via global_load_lds w=16.
// LDS ~54KB -> 2 blocks/CU (16 waves/CU, 4/SIMD). One barrier per K-iter.
// ---------------------------------------------------------------------------
__global__ __launch_bounds__(512, 4) void score_mfma(
    const float* __restrict__ x, const ushort* __restrict__ Wpk,
    const float* __restrict__ b1, const float* __restrict__ W2,
    const float* __restrict__ b2, float* __restrict__ scores,
    float* __restrict__ partials)
{
    __shared__ ushort As[2][128 * AP];
    __shared__ ushort Bs[2][16 * 512];
    __shared__ float zbuf[128][4];
    __shared__ float red[128];

    const int t    = threadIdx.x;
    const int lane = t & 63;
    const int w    = t >> 6;         // 0..7
    const int wr   = w >> 2;         // 0..1  (64 rows each)
    const int wc   = w & 3;          // 0..3  (64 cols each)
    const int l15  = lane & 15;
    const int lk   = lane >> 4;
    const size_t row0 = (size_t)blockIdx.x * 128;

    const int arow = t >> 2;         // 0..127
    const int aq   = t & 3;          // 8-float chunk of the 32-k slice
    const float* xbase = x + (row0 + arow) * DIM + aq * 8;

    f32x4 acc[4][4];
#pragma unroll
    for (int rf = 0; rf < 4; ++rf)
#pragma unroll
        for (int cf = 0; cf < 4; ++cf) acc[rf][cf] = (f32x4){0.f, 0.f, 0.f, 0.f};

    float pf[8];
#define LOADA(KT) { const float* xp = xbase + (KT) * BK; \
        *(float4*)&pf[0] = ((const float4*)xp)[0]; \
        *(float4*)&pf[4] = ((const float4*)xp)[1]; }
#define STOREA(BUF) { \
        ushort hb[8]; \
        _Pragma("unroll") \
        for (int j = 0; j < 8; ++j) hb[j] = (ushort)bf16_rne(pf[j]); \
        *(uint4*)&As[BUF][arow * AP + aq * 8] = *(uint4*)&hb[0]; }
#define LOADB(KT, BUF) { \
        _Pragma("unroll") \
        for (int i = 0; i < 2; ++i) { \
            const int g_ = w * 2 + i; \
            GLDS16(Wpk + (((size_t)(KT) * 16 + g_) * 64 + lane) * 8, \
                   &Bs[BUF][g_ * 512 + lane * 8]); \
        } }

    // prologue: stage kt=0
    LOADB(0, 0);
    LOADA(0);
    STOREA(0);
    __syncthreads();

    for (int kt = 0; kt < NKT; ++kt) {
        const int cur = kt & 1;
        const int nxt = cur ^ 1;
        if (kt < NKT - 1) {
            LOADB(kt + 1, nxt);
            LOADA(kt + 1);
        }
        bf16x8 Af[4];
#pragma unroll
        for (int rf = 0; rf < 4; ++rf) {
            const int row = wr * 64 + rf * 16 + l15;
            Af[rf] = *(const bf16x8*)&As[cur][row * AP + lk * 8];
        }
#pragma unroll
        for (int cf = 0; cf < 4; ++cf) {
            const bf16x8 Bf = *(const bf16x8*)&Bs[cur][(wc * 4 + cf) * 512 + lane * 8];
            acc[0][cf] = __builtin_amdgcn_mfma_f32_16x16x32_bf16(Af[0], Bf, acc[0][cf], 0, 0, 0);
            acc[1][cf] = __builtin_amdgcn_mfma_f32_16x16x32_bf16(Af[1], Bf, acc[1][cf], 0, 0, 0);
            acc[2][cf] = __builtin_amdgcn_mfma_f32_16x16x32_bf16(Af[2], Bf, acc[2][cf], 0, 0, 0);
            acc[3][cf] = __builtin_amdgcn_mfma_f32_16x16x32_bf16(Af[3], Bf, acc[3][cf], 0, 0, 0);
        }
        if (kt < NKT - 1) STOREA(nxt);
        __syncthreads();
    }

    // epilogue: z = sum_h relu(C + b1) * W2; C row = lk*4+j, col = l15
    float b1r[4], w2r[4];
#pragma unroll
    for (int cf = 0; cf < 4; ++cf) {
        const int col = wc * 64 + cf * 16 + l15;
        b1r[cf] = b1[col];
        w2r[cf] = W2[col];
    }
#pragma unroll
    for (int rf = 0; rf < 4; ++rf) {
#pragma unroll
        for (int j = 0; j < 4; ++j) {
            float z = 0.f;
#pragma unroll
            for (int cf = 0; cf < 4; ++cf)
                z = fmaf(fmaxf(acc[rf][cf][j] + b1r[cf], 0.f), w2r[cf], z);
            z += __shfl_xor(z, 1);
            z += __shfl_xor(z, 2);
            z += __shfl_xor(z, 4);
            z += __shfl_xor(z, 8);
            if (l15 == 0) zbuf[wr * 64 + rf * 16 + lk * 4 + j][wc] = z;
        }
    }
    __syncthreads();
    if (t < 128) {
        const float z = (zbuf[t][0] + zbuf[t][1]) + (zbuf[t][2] + zbuf[t][3]) + b2[0];
        const float s = 1.f / (1.f + expf(-z));
        scores[row0 + t] = s;
        red[t] = fabsf(s - 0.5f);
    }
    __syncthreads();
    for (int off = 64; off > 0; off >>= 1) {
        if (t < off) red[t] += red[t + off];
        __syncthreads();
    }
    if (t == 0) partials[blockIdx.x] = red[0];
}

// ---------------------------------------------------------------------------
// fixfind: per batch, binary-search the approx k-th score, emit rows within
// +-DELTA (deterministic order by row index).
// ---------------------------------------------------------------------------
__global__ __launch_bounds__(1024) void fixfind_kernel(
    const float* __restrict__ scores, int* __restrict__ winList,
    int* __restrict__ winCnt)
{
    const int b    = blockIdx.x;
    const int t    = threadIdx.x;
    const int lane = t & 63;
    const int wid  = t >> 6;
    __shared__ unsigned red[17];
    __shared__ unsigned wsum[16];

    float sv[16];
    unsigned bits[16];
    const float4* sp = (const float4*)(scores + (size_t)b * N_TOK + t * 16);
#pragma unroll
    for (int j = 0; j < 4; ++j) {
        const float4 v = sp[j];
        sv[j * 4 + 0] = v.x; sv[j * 4 + 1] = v.y;
        sv[j * 4 + 2] = v.z; sv[j * 4 + 3] = v.w;
    }
#pragma unroll
    for (int j = 0; j < 16; ++j) bits[j] = __float_as_uint(sv[j]);

    auto countGE = [&](unsigned v) -> unsigned {
        unsigned c = 0;
#pragma unroll
        for (int j = 0; j < 16; ++j) c += (bits[j] >= v) ? 1u : 0u;
        c += __shfl_xor(c, 32); c += __shfl_xor(c, 16); c += __shfl_xor(c, 8);
        c += __shfl_xor(c, 4);  c += __shfl_xor(c, 2);  c += __shfl_xor(c, 1);
        if (lane == 0) red[wid] = c;
        __syncthreads();
        if (t == 0) {
            unsigned s = 0;
            for (int w = 0; w < 16; ++w) s += red[w];
            red[16] = s;
        }
        __syncthreads();
        return red[16];
    };

    unsigned lo = 0u, hi = 0x40000000u;
    while (hi - lo > 1u) {
        const unsigned mid = (lo + hi) >> 1;
        if (countGE(mid) >= KEEP) lo = mid; else hi = mid;
    }
    const float sT = __uint_as_float(lo);

    int cnt = 0;
    bool inw[16];
#pragma unroll
    for (int j = 0; j < 16; ++j) {
        inw[j] = fabsf(sv[j] - sT) <= DELTA;
        cnt += inw[j] ? 1 : 0;
    }
    unsigned inc = (unsigned)cnt;
#pragma unroll
    for (int off = 1; off < 64; off <<= 1) {
        const unsigned n = __shfl_up(inc, off);
        if (lane >= off) inc += n;
    }
    const unsigned excl = inc - (unsigned)cnt;
    if (lane == 63) wsum[wid] = inc;
    __syncthreads();
    if (t == 0) {
        unsigned s = 0;
        for (int w = 0; w < 16; ++w) { const unsigned tmp = wsum[w]; wsum[w] = s; s += tmp; }
        winCnt[b] = (int)(s > WCAP ? WCAP : s);
    }
    __syncthreads();
    unsigned pos = wsum[wid] + excl;
#pragma unroll
    for (int j = 0; j < 16; ++j) {
        if (inw[j]) {
            if (pos < WCAP) winList[b * WCAP + pos] = t * 16 + j;
            ++pos;
        }
    }
}

// ---------------------------------------------------------------------------
// fix2: exact f32 recompute of windowed rows, 8 rows/group, 1024 threads,
// k-dim split over 4 thread-quads. Grid-stride over groups.
// ---------------------------------------------------------------------------
__global__ __launch_bounds__(1024) void fix2_kernel(
    const float* __restrict__ x, const float* __restrict__ W1,
    const float* __restrict__ b1, const float* __restrict__ W2,
    const float* __restrict__ b2, float* __restrict__ scores,
    const int* __restrict__ winList, const int* __restrict__ winCnt)
{
    __shared__ float xrT[1024][8];
    __shared__ float part[4][8][256];
    __shared__ int rows[8];

    const int t = threadIdx.x;
    int c[4], cum[5];
    cum[0] = 0;
    for (int b = 0; b < 4; ++b) {
        int cc = winCnt[b];
        if (cc > WCAP) cc = WCAP;
        if (cc < 0) cc = 0;
        c[b] = cc;
        cum[b + 1] = cum[b] + ((cc + 7) >> 3);
    }
    for (int g = blockIdx.x; g < cum[4]; g += gridDim.x) {
        int b = 0;
        while (g >= cum[b + 1]) ++b;
        const int gi   = g - cum[b];
        const int nval = min(8, c[b] - gi * 8);
        if (t < 8)
            rows[t] = winList[b * WCAP + gi * 8 + (t < nval ? t : 0)];
        __syncthreads();
        {
            const int r = t >> 7, c0 = (t & 127) * 8;
            const float* xp = x + ((size_t)b * N_TOK + rows[r]) * DIM + c0;
            const float4 a = ((const float4*)xp)[0], bq = ((const float4*)xp)[1];
            xrT[c0 + 0][r] = a.x;  xrT[c0 + 1][r] = a.y;
            xrT[c0 + 2][r] = a.z;  xrT[c0 + 3][r] = a.w;
            xrT[c0 + 4][r] = bq.x; xrT[c0 + 5][r] = bq.y;
            xrT[c0 + 6][r] = bq.z; xrT[c0 + 7][r] = bq.w;
        }
        __syncthreads();
        const int h = t & 255, q = t >> 8;
        float a8[8];
#pragma unroll
        for (int r = 0; r < 8; ++r) a8[r] = 0.f;
        const int k0 = q * 256;
        for (int k = 0; k < 256; ++k) {
            const float wv = W1[(size_t)(k0 + k) * HID + h];
            const float4 xa = *(const float4*)&xrT[k0 + k][0];
            const float4 xb = *(const float4*)&xrT[k0 + k][4];
            a8[0] = fmaf(xa.x, wv, a8[0]); a8[1] = fmaf(xa.y, wv, a8[1]);
            a8[2] = fmaf(xa.z, wv, a8[2]); a8[3] = fmaf(xa.w, wv, a8[3]);
            a8[4] = fmaf(xb.x, wv, a8[4]); a8[5] = fmaf(xb.y, wv, a8[5]);
            a8[6] = fmaf(xb.z, wv, a8[6]); a8[7] = fmaf(xb.w, wv, a8[7]);
        }
#pragma unroll
        for (int r = 0; r < 8; ++r) part[q][r][h] = a8[r];
        __syncthreads();
        const int wid = t >> 6, lane = t & 63;
        if (wid < 8) {
            const int r = wid;
            float v = 0.f;
#pragma unroll
            for (int i = 0; i < 4; ++i) {
                const int hc = i * 64 + lane;
                float hv = (part[0][r][hc] + part[1][r][hc]) + (part[2][r][hc] + part[3][r][hc]);
                hv = fmaxf(hv + b1[hc], 0.f);
                v = fmaf(hv, W2[hc], v);
            }
            v += __shfl_xor(v, 32); v += __shfl_xor(v, 16); v += __shfl_xor(v, 8);
            v += __shfl_xor(v, 4);  v += __shfl_xor(v, 2);  v += __shfl_xor(v, 1);
            if (lane == 0 && r < nval)
                scores[(size_t)b * N_TOK + rows[r]] = 1.f / (1.f + expf(-(v + b2[0])));
        }
        __syncthreads();
    }
}

// ---------------------------------------------------------------------------
// select: exact top-k per batch on corrected scores (verified).
// ---------------------------------------------------------------------------
__global__ __launch_bounds__(1024) void select_kernel(
    const float* __restrict__ scores, int* __restrict__ idxList)
{
    const int b    = blockIdx.x;
    const int t    = threadIdx.x;
    const int lane = t & 63;
    const int wid  = t >> 6;
    __shared__ unsigned red[17];

    unsigned bits[16];
    const float4* sp = (const float4*)(scores + (size_t)b * N_TOK + t * 16);
#pragma unroll
    for (int j = 0; j < 4; ++j) {
        const float4 v = sp[j];
        bits[j * 4 + 0] = __float_as_uint(v.x);
        bits[j * 4 + 1] = __float_as_uint(v.y);
        bits[j * 4 + 2] = __float_as_uint(v.z);
        bits[j * 4 + 3] = __float_as_uint(v.w);
    }

    auto countGE = [&](unsigned v) -> unsigned {
        unsigned c = 0;
#pragma unroll
        for (int j = 0; j < 16; ++j) c += (bits[j] >= v) ? 1u : 0u;
        c += __shfl_xor(c, 32); c += __shfl_xor(c, 16); c += __shfl_xor(c, 8);
        c += __shfl_xor(c, 4);  c += __shfl_xor(c, 2);  c += __shfl_xor(c, 1);
        if (lane == 0) red[wid] = c;
        __syncthreads();
        if (t == 0) {
            unsigned s = 0;
            for (int w = 0; w < 16; ++w) s += red[w];
            red[16] = s;
        }
        __syncthreads();
        return red[16];
    };

    unsigned lo = 0u, hi = 0x40000000u;
    while (hi - lo > 1u) {
        const unsigned mid = (lo + hi) >> 1;
        if (countGE(mid) >= KEEP) lo = mid; else hi = mid;
    }
    const unsigned T    = lo;
    const unsigned cGT  = countGE(T + 1u);
    const unsigned need = KEEP - cGT;

    unsigned pre[16];
    unsigned run = 0;
#pragma unroll
    for (int j = 0; j < 16; ++j) {
        pre[j] = run;
        const unsigned gt = (bits[j] > T) ? 1u : 0u;
        const unsigned eq = (bits[j] == T) ? 1u : 0u;
        run += gt | (eq << 16);
    }
    unsigned inc = run;
#pragma unroll
    for (int off = 1; off < 64; off <<= 1) {
        const unsigned n = __shfl_up(inc, off);
        if (lane >= off) inc += n;
    }
    const unsigned waveExcl = inc - run;
    if (lane == 63) red[wid] = inc;
    __syncthreads();
    if (t == 0) {
        unsigned s = 0;
        for (int w = 0; w < 16; ++w) { const unsigned tmp = red[w]; red[w] = s; s += tmp; }
    }
    __syncthreads();
    const unsigned base = red[wid] + waveExcl;

#pragma unroll
    for (int j = 0; j < 16; ++j) {
        const unsigned pe    = base + pre[j];
        const unsigned tieR  = pe >> 16;
        const unsigned posGT = pe & 0xFFFFu;
        const bool gt = bits[j] > T;
        const bool eq = bits[j] == T;
        if (gt || (eq && tieR < need)) {
            const unsigned pos = posGT + (tieR < need ? tieR : need);
            idxList[(size_t)b * KEEP + pos] = t * 16 + j;
        }
    }
}

// ---------------------------------------------------------------------------
// gather: weighted gather, float4 (HBM-bound).
// ---------------------------------------------------------------------------
__global__ __launch_bounds__(256) void gather_kernel(
    const float* __restrict__ x, const float* __restrict__ scores,
    const int* __restrict__ idxList, float* __restrict__ out)
{
    const int t = threadIdx.x;
#pragma unroll
    for (int q = 0; q < 4; ++q) {
        const int orow = blockIdx.x * 4 + q;
        const int b    = orow / KEEP;
        const int idx  = idxList[orow];
        const float s  = scores[(size_t)b * N_TOK + idx];
        const float4 v = *(const float4*)(x + (((size_t)b * N_TOK + idx) << 10) + t * 4);
        float4 o;
        o.x = v.x * s; o.y = v.y * s; o.z = v.z * s; o.w = v.w * s;
        *(float4*)(out + ((size_t)orow << 10) + t * 4) = o;
    }
}

// ---------------------------------------------------------------------------
// loss: -mean(|s-0.5|) over 512 block partials.
// ---------------------------------------------------------------------------
__global__ __launch_bounds__(256) void loss_kernel(
    const float* __restrict__ partials, float* __restrict__ outLoss)
{
    __shared__ float red[256];
    const int t = threadIdx.x;
    red[t] = partials[t] + partials[t + 256];
    __syncthreads();
    for (int off = 128; off > 0; off >>= 1) {
        if (t < off) red[t] += red[t + off];
        __syncthreads();
    }
    if (t == 0) outLoss[0] = -(red[0] / (float)MROWS);
}

extern "C" void kernel_launch(void* const* d_in, const int* in_sizes, int n_in,
                              void* d_out, int out_size, void* d_ws, size_t ws_size,
                              hipStream_t stream)
{
    const float* x  = (const float*)d_in[0];
    const float* W1 = (const float*)d_in[1];
    const float* b1 = (const float*)d_in[2];
    const float* W2 = (const float*)d_in[3];
    const float* b2 = (const float*)d_in[4];
    float* out = (float*)d_out;

    char* ws = (char*)d_ws;
    float* scores   = (float*)ws;                 // 262144 B
    float* partials = (float*)(ws + 262144);      // 4096 B (512 used)
    int*   idxList  = (int*)(ws + 266240);        // 183488 B
    ushort* Wpk     = (ushort*)(ws + 458752);     // 524288 B
    int*   winList  = (int*)(ws + 983040);        // 65536 B
    int*   winCnt   = (int*)(ws + 1048576);       // 16 B

    prep_kernel<<<16, 256, 0, stream>>>(W1, Wpk);
    score_mfma<<<MROWS / 128, 512, 0, stream>>>(x, Wpk, b1, W2, b2, scores, partials);
    loss_kernel<<<1, 256, 0, stream>>>(partials, out + (size_t)BATCH * KEEP * DIM);
    fixfind_kernel<<<BATCH, 1024, 0, stream>>>(scores, winList, winCnt);
    fix2_kernel<<<256, 1024, 0, stream>>>(x, W1, b1, W2, b2, scores, winList, winCnt);
    select_kernel<<<BATCH, 1024, 0, stream>>>(scores, idxList);
    gather_kernel<<<KEEP, 256, 0, stream>>>(x, scores, idxList, out);
}

// Round 6
// 227.706 us; speedup vs baseline: 1.4293x; 1.0075x over previous
//
#include <hip/hip_runtime.h>
#include <hip/hip_bf16.h>
#include <math.h>

#define N_TOK 16384
#define BATCH 4
#define DIM   1024
#define HID   256
#define KEEP  11468            // int(16384 * 0.7)
#define MROWS 65536
#define BK    32
#define NKT   (DIM / BK)       // 32 K-iters
#define DELTA 6e-3f            // exact-recompute window around approx cut
#define WCAP  4096             // max window rows per batch
#define AP    40               // A row pitch in ushorts (80B: 2-way bank alias = free)
#define ASLOT (128 * AP)       // 5120 ushorts per A slot
#define BSLOT (16 * 512)       // 8192 ushorts per B slot

typedef __attribute__((ext_vector_type(8))) short bf16x8;
typedef __attribute__((ext_vector_type(4))) float f32x4;

__device__ inline unsigned bf16_rne(float f) {
    unsigned u = __float_as_uint(f);
    return (u + 0x7FFFu + ((u >> 16) & 1u)) >> 16;
}

#define GLDS16(gp, lp) __builtin_amdgcn_global_load_lds( \
    (const __attribute__((address_space(1))) void*)(gp), \
    (__attribute__((address_space(3))) void*)(lp), 16, 0, 0)

// ---------------------------------------------------------------------------
// prep: pack W1 (f32 [k][h]) into MFMA-B-fragment lines, bf16:
// line L = K32*16 + hg; within line: lane&15 = h offset, (lane>>4)*8+j = k.
// ---------------------------------------------------------------------------
__global__ __launch_bounds__(256) void prep_kernel(
    const float* __restrict__ W1, ushort* __restrict__ Wpk)
{
    const int kt = blockIdx.x;   // 0..15
    for (int idx = threadIdx.x; idx < 2048; idx += 256) {
        const int lane = idx & 63;
        const int g    = idx >> 6;        // 0..31
        const int h    = (g & 15) * 16 + (lane & 15);
        const int kb   = kt * 64 + (g >> 4) * 32 + (lane >> 4) * 8;
        ushort v[8];
#pragma unroll
        for (int j = 0; j < 8; ++j)
            v[j] = (ushort)bf16_rne(W1[(size_t)(kb + j) * HID + h]);
        *(uint4*)(Wpk + ((size_t)(kt * 32 + g) * 64 + lane) * 8) = *(uint4*)v;
    }
}

// ---------------------------------------------------------------------------
// score: scores = sigmoid(relu(x@W1+b1)@W2+b2), 1-pass bf16 MFMA.
// 512 thr = 8 waves (2 wr x 4 wc), tile 128 x 256, BK=32, 32 iters.
// Deep pipeline: 3-slot circular LDS for A and B; counted vmcnt(4) (never 0
// in main loop) + raw s_barrier so prefetch loads stay in flight across
// barriers (T3/T4). A reg-staged f32->bf16; B via global_load_lds w=16.
// LDS 78KB -> 2 blocks/CU at VGPR<=128.
// ---------------------------------------------------------------------------
__global__ __launch_bounds__(512, 4) void score_mfma(
    const float* __restrict__ x, const ushort* __restrict__ Wpk,
    const float* __restrict__ b1, const float* __restrict__ W2,
    const float* __restrict__ b2, float* __restrict__ scores,
    float* __restrict__ partials)
{
    __shared__ ushort AsAll[3 * ASLOT];
    __shared__ ushort BsAll[3 * BSLOT];

    const int t    = threadIdx.x;
    const int lane = t & 63;
    const int w    = t >> 6;         // 0..7
    const int wr   = w >> 2;         // 0..1  (64 rows each)
    const int wc   = w & 3;          // 0..3  (64 cols each)
    const int l15  = lane & 15;
    const int lk   = lane >> 4;
    const size_t row0 = (size_t)blockIdx.x * 128;

    const int arow = t >> 2;         // 0..127
    const int aq   = t & 3;          // 8-float chunk of 32-k slice
    const float* xbase = x + (row0 + arow) * DIM + aq * 8;

    f32x4 acc[4][4];
#pragma unroll
    for (int rf = 0; rf < 4; ++rf)
#pragma unroll
        for (int cf = 0; cf < 4; ++cf) acc[rf][cf] = (f32x4){0.f, 0.f, 0.f, 0.f};

    float4 p0a, p0b, p1a, p1b;       // two A prefetch register sets

#define ISSUEA(KT, PA, PB) { \
        const float4* xp = (const float4*)(xbase + (size_t)(KT) * BK); \
        PA = xp[0]; PB = xp[1]; }
#define CONVA(PA, PB, SLOT) { \
        ushort hb[8]; \
        hb[0] = (ushort)bf16_rne(PA.x); hb[1] = (ushort)bf16_rne(PA.y); \
        hb[2] = (ushort)bf16_rne(PA.z); hb[3] = (ushort)bf16_rne(PA.w); \
        hb[4] = (ushort)bf16_rne(PB.x); hb[5] = (ushort)bf16_rne(PB.y); \
        hb[6] = (ushort)bf16_rne(PB.z); hb[7] = (ushort)bf16_rne(PB.w); \
        *(uint4*)&AsAll[(SLOT) * ASLOT + arow * AP + aq * 8] = *(uint4*)&hb[0]; }
#define ISSUEB(KT, SLOT) { \
        _Pragma("unroll") \
        for (int i = 0; i < 2; ++i) { \
            const int g_ = w * 2 + i; \
            GLDS16(Wpk + (((size_t)(KT) * 16 + g_) * 64 + lane) * 8, \
                   &BsAll[(SLOT) * BSLOT + g_ * 512 + lane * 8]); \
        } }
#define COMPUTE(SLOT) { \
        bf16x8 Af[4]; \
        _Pragma("unroll") \
        for (int rf = 0; rf < 4; ++rf) { \
            const int row = wr * 64 + rf * 16 + l15; \
            Af[rf] = *(const bf16x8*)&AsAll[(SLOT) * ASLOT + row * AP + lk * 8]; \
        } \
        _Pragma("unroll") \
        for (int cf = 0; cf < 4; ++cf) { \
            const bf16x8 Bf = *(const bf16x8*)&BsAll[(SLOT) * BSLOT + (wc * 4 + cf) * 512 + lane * 8]; \
            acc[0][cf] = __builtin_amdgcn_mfma_f32_16x16x32_bf16(Af[0], Bf, acc[0][cf], 0, 0, 0); \
            acc[1][cf] = __builtin_amdgcn_mfma_f32_16x16x32_bf16(Af[1], Bf, acc[1][cf], 0, 0, 0); \
            acc[2][cf] = __builtin_amdgcn_mfma_f32_16x16x32_bf16(Af[2], Bf, acc[2][cf], 0, 0, 0); \
            acc[3][cf] = __builtin_amdgcn_mfma_f32_16x16x32_bf16(Af[3], Bf, acc[3][cf], 0, 0, 0); \
        } }

    // ---- prologue: B(0)->slot0, A(0)->set0, A(1)->set1, write A(0)->slot0
    ISSUEB(0, 0);
    ISSUEA(0, p0a, p0b);
    ISSUEA(1, p1a, p1b);
    CONVA(p0a, p0b, 0);              // compiler waits A(0); drains B(0) too
    asm volatile("s_waitcnt lgkmcnt(0)" ::: "memory");
    __builtin_amdgcn_s_barrier();
    __builtin_amdgcn_sched_barrier(0);

    for (int kt = 0; kt < NKT; ++kt) {
        if (kt < NKT - 2) {          // issue A(kt+2) into set kt%2
            if ((kt & 1) == 0) { ISSUEA(kt + 2, p0a, p0b); }
            else               { ISSUEA(kt + 2, p1a, p1b); }
        }
        if (kt < NKT - 1) {          // issue B(kt+1); convert+write A(kt+1)
            const int s1 = (kt + 1) % 3;
            ISSUEB(kt + 1, s1);
            if ((kt & 1) == 0) { CONVA(p1a, p1b, s1); }
            else               { CONVA(p0a, p0b, s1); }
        }
        // counted drain: leave the 4 newest VMEM ops (A(kt+2)x2, B(kt+1)x2)
        // in flight; guarantees tile kt fully landed. Tail tightens.
        if (kt < NKT - 2)       asm volatile("s_waitcnt vmcnt(4)" ::: "memory");
        else if (kt == NKT - 2) asm volatile("s_waitcnt vmcnt(2)" ::: "memory");
        else                    asm volatile("s_waitcnt vmcnt(0)" ::: "memory");
        asm volatile("s_waitcnt lgkmcnt(0)" ::: "memory");
        __builtin_amdgcn_s_barrier();
        __builtin_amdgcn_sched_barrier(0);
        COMPUTE(kt % 3);
    }

    // ---- epilogue: z = sum_h relu(C + b1) * W2; C row = lk*4+j, col = l15
    // zbuf/red aliased onto Bs slot 0 (last computes read slots 1; disjoint).
    float* zb = (float*)&BsAll[0];        // [128][4]
    float* rd = (float*)&BsAll[1024];     // [128]
    float b1r[4], w2r[4];
#pragma unroll
    for (int cf = 0; cf < 4; ++cf) {
        const int col = wc * 64 + cf * 16 + l15;
        b1r[cf] = b1[col];
        w2r[cf] = W2[col];
    }
#pragma unroll
    for (int rf = 0; rf < 4; ++rf) {
#pragma unroll
        for (int j = 0; j < 4; ++j) {
            float z = 0.f;
#pragma unroll
            for (int cf = 0; cf < 4; ++cf)
                z = fmaf(fmaxf(acc[rf][cf][j] + b1r[cf], 0.f), w2r[cf], z);
            z += __shfl_xor(z, 1);
            z += __shfl_xor(z, 2);
            z += __shfl_xor(z, 4);
            z += __shfl_xor(z, 8);
            if (l15 == 0) zb[(wr * 64 + rf * 16 + lk * 4 + j) * 4 + wc] = z;
        }
    }
    __syncthreads();
    if (t < 128) {
        const float z = (zb[t * 4 + 0] + zb[t * 4 + 1]) + (zb[t * 4 + 2] + zb[t * 4 + 3]) + b2[0];
        const float s = 1.f / (1.f + expf(-z));
        scores[row0 + t] = s;
        rd[t] = fabsf(s - 0.5f);
    }
    __syncthreads();
    for (int off = 64; off > 0; off >>= 1) {
        if (t < off) rd[t] += rd[t + off];
        __syncthreads();
    }
    if (t == 0) partials[blockIdx.x] = rd[0];
}

// ---------------------------------------------------------------------------
// fixfind: per batch, binary-search the approx k-th score, emit rows within
// +-DELTA (deterministic order by row index). Wave-parallel count reduce.
// ---------------------------------------------------------------------------
__global__ __launch_bounds__(1024) void fixfind_kernel(
    const float* __restrict__ scores, int* __restrict__ winList,
    int* __restrict__ winCnt)
{
    const int b    = blockIdx.x;
    const int t    = threadIdx.x;
    const int lane = t & 63;
    const int wid  = t >> 6;
    __shared__ unsigned red[17];
    __shared__ unsigned wsum[16];

    float sv[16];
    unsigned bits[16];
    const float4* sp = (const float4*)(scores + (size_t)b * N_TOK + t * 16);
#pragma unroll
    for (int j = 0; j < 4; ++j) {
        const float4 v = sp[j];
        sv[j * 4 + 0] = v.x; sv[j * 4 + 1] = v.y;
        sv[j * 4 + 2] = v.z; sv[j * 4 + 3] = v.w;
    }
#pragma unroll
    for (int j = 0; j < 16; ++j) bits[j] = __float_as_uint(sv[j]);

    auto countGE = [&](unsigned v) -> unsigned {
        unsigned c = 0;
#pragma unroll
        for (int j = 0; j < 16; ++j) c += (bits[j] >= v) ? 1u : 0u;
        c += __shfl_xor(c, 32); c += __shfl_xor(c, 16); c += __shfl_xor(c, 8);
        c += __shfl_xor(c, 4);  c += __shfl_xor(c, 2);  c += __shfl_xor(c, 1);
        if (lane == 0) red[wid] = c;
        __syncthreads();
        if (wid == 0) {
            unsigned s = (lane < 16) ? red[lane] : 0u;
            s += __shfl_xor(s, 8); s += __shfl_xor(s, 4);
            s += __shfl_xor(s, 2); s += __shfl_xor(s, 1);
            if (lane == 0) red[16] = s;
        }
        __syncthreads();
        return red[16];
    };

    unsigned lo = 0u, hi = 0x40000000u;
    while (hi - lo > 1u) {
        const unsigned mid = (lo + hi) >> 1;
        if (countGE(mid) >= KEEP) lo = mid; else hi = mid;
    }
    const float sT = __uint_as_float(lo);

    int cnt = 0;
    bool inw[16];
#pragma unroll
    for (int j = 0; j < 16; ++j) {
        inw[j] = fabsf(sv[j] - sT) <= DELTA;
        cnt += inw[j] ? 1 : 0;
    }
    unsigned inc = (unsigned)cnt;
#pragma unroll
    for (int off = 1; off < 64; off <<= 1) {
        const unsigned n = __shfl_up(inc, off);
        if (lane >= off) inc += n;
    }
    const unsigned excl = inc - (unsigned)cnt;
    if (lane == 63) wsum[wid] = inc;
    __syncthreads();
    if (t == 0) {
        unsigned s = 0;
        for (int w = 0; w < 16; ++w) { const unsigned tmp = wsum[w]; wsum[w] = s; s += tmp; }
        winCnt[b] = (int)(s > WCAP ? WCAP : s);
    }
    __syncthreads();
    unsigned pos = wsum[wid] + excl;
#pragma unroll
    for (int j = 0; j < 16; ++j) {
        if (inw[j]) {
            if (pos < WCAP) winList[b * WCAP + pos] = t * 16 + j;
            ++pos;
        }
    }
}

// ---------------------------------------------------------------------------
// fix2: exact f32 recompute of windowed rows, 8 rows/group, 1024 threads,
// k-dim split over 4 thread-quads. Grid-stride over groups.
// ---------------------------------------------------------------------------
__global__ __launch_bounds__(1024) void fix2_kernel(
    const float* __restrict__ x, const float* __restrict__ W1,
    const float* __restrict__ b1, const float* __restrict__ W2,
    const float* __restrict__ b2, float* __restrict__ scores,
    const int* __restrict__ winList, const int* __restrict__ winCnt)
{
    __shared__ float xrT[1024][8];
    __shared__ float part[4][8][256];
    __shared__ int rows[8];

    const int t = threadIdx.x;
    int c[4], cum[5];
    cum[0] = 0;
    for (int b = 0; b < 4; ++b) {
        int cc = winCnt[b];
        if (cc > WCAP) cc = WCAP;
        if (cc < 0) cc = 0;
        c[b] = cc;
        cum[b + 1] = cum[b] + ((cc + 7) >> 3);
    }
    for (int g = blockIdx.x; g < cum[4]; g += gridDim.x) {
        int b = 0;
        while (g >= cum[b + 1]) ++b;
        const int gi   = g - cum[b];
        const int nval = min(8, c[b] - gi * 8);
        if (t < 8)
            rows[t] = winList[b * WCAP + gi * 8 + (t < nval ? t : 0)];
        __syncthreads();
        {
            const int r = t >> 7, c0 = (t & 127) * 8;
            const float* xp = x + ((size_t)b * N_TOK + rows[r]) * DIM + c0;
            const float4 a = ((const float4*)xp)[0], bq = ((const float4*)xp)[1];
            xrT[c0 + 0][r] = a.x;  xrT[c0 + 1][r] = a.y;
            xrT[c0 + 2][r] = a.z;  xrT[c0 + 3][r] = a.w;
            xrT[c0 + 4][r] = bq.x; xrT[c0 + 5][r] = bq.y;
            xrT[c0 + 6][r] = bq.z; xrT[c0 + 7][r] = bq.w;
        }
        __syncthreads();
        const int h = t & 255, q = t >> 8;
        float a8[8];
#pragma unroll
        for (int r = 0; r < 8; ++r) a8[r] = 0.f;
        const int k0 = q * 256;
        for (int k = 0; k < 256; ++k) {
            const float wv = W1[(size_t)(k0 + k) * HID + h];
            const float4 xa = *(const float4*)&xrT[k0 + k][0];
            const float4 xb = *(const float4*)&xrT[k0 + k][4];
            a8[0] = fmaf(xa.x, wv, a8[0]); a8[1] = fmaf(xa.y, wv, a8[1]);
            a8[2] = fmaf(xa.z, wv, a8[2]); a8[3] = fmaf(xa.w, wv, a8[3]);
            a8[4] = fmaf(xb.x, wv, a8[4]); a8[5] = fmaf(xb.y, wv, a8[5]);
            a8[6] = fmaf(xb.z, wv, a8[6]); a8[7] = fmaf(xb.w, wv, a8[7]);
        }
#pragma unroll
        for (int r = 0; r < 8; ++r) part[q][r][h] = a8[r];
        __syncthreads();
        const int wid = t >> 6, lane = t & 63;
        if (wid < 8) {
            const int r = wid;
            float v = 0.f;
#pragma unroll
            for (int i = 0; i < 4; ++i) {
                const int hc = i * 64 + lane;
                float hv = (part[0][r][hc] + part[1][r][hc]) + (part[2][r][hc] + part[3][r][hc]);
                hv = fmaxf(hv + b1[hc], 0.f);
                v = fmaf(hv, W2[hc], v);
            }
            v += __shfl_xor(v, 32); v += __shfl_xor(v, 16); v += __shfl_xor(v, 8);
            v += __shfl_xor(v, 4);  v += __shfl_xor(v, 2);  v += __shfl_xor(v, 1);
            if (lane == 0 && r < nval)
                scores[(size_t)b * N_TOK + rows[r]] = 1.f / (1.f + expf(-(v + b2[0])));
        }
        __syncthreads();
    }
}

// ---------------------------------------------------------------------------
// select: exact top-k per batch on corrected scores; wave-parallel reduce.
// ---------------------------------------------------------------------------
__global__ __launch_bounds__(1024) void select_kernel(
    const float* __restrict__ scores, int* __restrict__ idxList)
{
    const int b    = blockIdx.x;
    const int t    = threadIdx.x;
    const int lane = t & 63;
    const int wid  = t >> 6;
    __shared__ unsigned red[17];

    unsigned bits[16];
    const float4* sp = (const float4*)(scores + (size_t)b * N_TOK + t * 16);
#pragma unroll
    for (int j = 0; j < 4; ++j) {
        const float4 v = sp[j];
        bits[j * 4 + 0] = __float_as_uint(v.x);
        bits[j * 4 + 1] = __float_as_uint(v.y);
        bits[j * 4 + 2] = __float_as_uint(v.z);
        bits[j * 4 + 3] = __float_as_uint(v.w);
    }

    auto countGE = [&](unsigned v) -> unsigned {
        unsigned c = 0;
#pragma unroll
        for (int j = 0; j < 16; ++j) c += (bits[j] >= v) ? 1u : 0u;
        c += __shfl_xor(c, 32); c += __shfl_xor(c, 16); c += __shfl_xor(c, 8);
        c += __shfl_xor(c, 4);  c += __shfl_xor(c, 2);  c += __shfl_xor(c, 1);
        if (lane == 0) red[wid] = c;
        __syncthreads();
        if (wid == 0) {
            unsigned s = (lane < 16) ? red[lane] : 0u;
            s += __shfl_xor(s, 8); s += __shfl_xor(s, 4);
            s += __shfl_xor(s, 2); s += __shfl_xor(s, 1);
            if (lane == 0) red[16] = s;
        }
        __syncthreads();
        return red[16];
    };

    unsigned lo = 0u, hi = 0x40000000u;
    while (hi - lo > 1u) {
        const unsigned mid = (lo + hi) >> 1;
        if (countGE(mid) >= KEEP) lo = mid; else hi = mid;
    }
    const unsigned T    = lo;
    const unsigned cGT  = countGE(T + 1u);
    const unsigned need = KEEP - cGT;

    unsigned pre[16];
    unsigned run = 0;
#pragma unroll
    for (int j = 0; j < 16; ++j) {
        pre[j] = run;
        const unsigned gt = (bits[j] > T) ? 1u : 0u;
        const unsigned eq = (bits[j] == T) ? 1u : 0u;
        run += gt | (eq << 16);
    }
    unsigned inc = run;
#pragma unroll
    for (int off = 1; off < 64; off <<= 1) {
        const unsigned n = __shfl_up(inc, off);
        if (lane >= off) inc += n;
    }
    const unsigned waveExcl = inc - run;
    if (lane == 63) red[wid] = inc;
    __syncthreads();
    if (t == 0) {
        unsigned s = 0;
        for (int w = 0; w < 16; ++w) { const unsigned tmp = red[w]; red[w] = s; s += tmp; }
    }
    __syncthreads();
    const unsigned base = red[wid] + waveExcl;

#pragma unroll
    for (int j = 0; j < 16; ++j) {
        const unsigned pe    = base + pre[j];
        const unsigned tieR  = pe >> 16;
        const unsigned posGT = pe & 0xFFFFu;
        const bool gt = bits[j] > T;
        const bool eq = bits[j] == T;
        if (gt || (eq && tieR < need)) {
            const unsigned pos = posGT + (tieR < need ? tieR : need);
            idxList[(size_t)b * KEEP + pos] = t * 16 + j;
        }
    }
}

// ---------------------------------------------------------------------------
// gather: weighted gather, float4 (HBM-bound, near roofline).
// ---------------------------------------------------------------------------
__global__ __launch_bounds__(256) void gather_kernel(
    const float* __restrict__ x, const float* __restrict__ scores,
    const int* __restrict__ idxList, float* __restrict__ out)
{
    const int t = threadIdx.x;
#pragma unroll
    for (int q = 0; q < 4; ++q) {
        const int orow = blockIdx.x * 4 + q;
        const int b    = orow / KEEP;
        const int idx  = idxList[orow];
        const float s  = scores[(size_t)b * N_TOK + idx];
        const float4 v = *(const float4*)(x + (((size_t)b * N_TOK + idx) << 10) + t * 4);
        float4 o;
        o.x = v.x * s; o.y = v.y * s; o.z = v.z * s; o.w = v.w * s;
        *(float4*)(out + ((size_t)orow << 10) + t * 4) = o;
    }
}

// ---------------------------------------------------------------------------
// loss: -mean(|s-0.5|) over 512 block partials.
// ---------------------------------------------------------------------------
__global__ __launch_bounds__(256) void loss_kernel(
    const float* __restrict__ partials, float* __restrict__ outLoss)
{
    __shared__ float red[256];
    const int t = threadIdx.x;
    red[t] = partials[t] + partials[t + 256];
    __syncthreads();
    for (int off = 128; off > 0; off >>= 1) {
        if (t < off) red[t] += red[t + off];
        __syncthreads();
    }
    if (t == 0) outLoss[0] = -(red[0] / (float)MROWS);
}

extern "C" void kernel_launch(void* const* d_in, const int* in_sizes, int n_in,
                              void* d_out, int out_size, void* d_ws, size_t ws_size,
                              hipStream_t stream)
{
    const float* x  = (const float*)d_in[0];
    const float* W1 = (const float*)d_in[1];
    const float* b1 = (const float*)d_in[2];
    const float* W2 = (const float*)d_in[3];
    const float* b2 = (const float*)d_in[4];
    float* out = (float*)d_out;

    char* ws = (char*)d_ws;
    float* scores   = (float*)ws;                 // 262144 B
    float* partials = (float*)(ws + 262144);      // 4096 B (512 used)
    int*   idxList  = (int*)(ws + 266240);        // 183488 B
    ushort* Wpk     = (ushort*)(ws + 458752);     // 524288 B
    int*   winList  = (int*)(ws + 983040);        // 65536 B
    int*   winCnt   = (int*)(ws + 1048576);       // 16 B

    prep_kernel<<<16, 256, 0, stream>>>(W1, Wpk);
    score_mfma<<<MROWS / 128, 512, 0, stream>>>(x, Wpk, b1, W2, b2, scores, partials);
    loss_kernel<<<1, 256, 0, stream>>>(partials, out + (size_t)BATCH * KEEP * DIM);
    fixfind_kernel<<<BATCH, 1024, 0, stream>>>(scores, winList, winCnt);
    fix2_kernel<<<256, 1024, 0, stream>>>(x, W1, b1, W2, b2, scores, winList, winCnt);
    select_kernel<<<BATCH, 1024, 0, stream>>>(scores, idxList);
    gather_kernel<<<KEEP, 256, 0, stream>>>(x, scores, idxList, out);
}